// Round 1
// baseline (1029.396 us; speedup 1.0000x reference)
//
#include <hip/hip_runtime.h>

#define BB 2
#define CH_FEAT 128
#define HEADS 4
#define DH 64
#define INNER 256
#define NPOS 13824   // 24^3
#define MPOS 512     // 8^3
#define DSZ 24

// ---------------- map q/v projection: mqv = map_qv_w @ smap, head-split ----
__global__ __launch_bounds__(512) void k_map_qv(const float* __restrict__ smap,
                                                const float* __restrict__ w,
                                                float* __restrict__ mapq,
                                                float* __restrict__ mapv) {
  int bm = blockIdx.x;
  int b = bm >> 9, m = bm & 511;
  __shared__ float s[64];
  int t = threadIdx.x;
  if (t < 64) s[t] = smap[(size_t)(b * 64 + t) * MPOS + m];
  __syncthreads();
  const float* wr = w + t * 64;
  float acc = 0.f;
#pragma unroll
  for (int c = 0; c < 64; ++c) acc += wr[c] * s[c];
  int qv = t >> 8, c2 = t & 255, head = c2 & 3, dh = c2 >> 2;
  float* dst = qv ? mapv : mapq;
  float val = qv ? acc : acc * 0.125f;  // fold attention scale into map_q
  dst[(((size_t)b * HEADS + head) * MPOS + m) * DH + dh] = val;
}

// ---------------- depthwise 3x3x3 SAME conv (generic channel count) --------
__global__ __launch_bounds__(256) void k_dw(const float* __restrict__ in,
                                            const float* __restrict__ w,
                                            float* __restrict__ out, int C) {
  int idx = blockIdx.x * 256 + threadIdx.x;
  int n = idx % NPOS;
  int bc = idx / NPOS;
  int c = bc % C;
  int x = n % DSZ, y = (n / DSZ) % DSZ, z = n / (DSZ * DSZ);
  const float* wr = w + c * 27;
  const float* ip = in + (size_t)bc * NPOS;
  float acc = 0.f;
#pragma unroll
  for (int dz = -1; dz <= 1; ++dz) {
    int zz = z + dz;
    if (zz < 0 || zz >= DSZ) continue;
#pragma unroll
    for (int dy = -1; dy <= 1; ++dy) {
      int yy = y + dy;
      if (yy < 0 || yy >= DSZ) continue;
#pragma unroll
      for (int dx = -1; dx <= 1; ++dx) {
        int xx = x + dx;
        if (xx < 0 || xx >= DSZ) continue;
        acc += wr[(dz + 1) * 9 + (dy + 1) * 3 + (dx + 1)] *
               ip[(zz * DSZ + yy) * DSZ + xx];
      }
    }
  }
  out[idx] = acc;
}

// ---------------- pointwise qv GEMM: [512,128] x dwt -> fq/fv head-split ---
__global__ __launch_bounds__(256) void k_pw_qv(const float* __restrict__ dwt,
                                               const float* __restrict__ pw,
                                               float* __restrict__ fq,
                                               float* __restrict__ fv) {
  __shared__ __align__(16) float sA[128][68];  // dwt[k][n]
  __shared__ __align__(16) float sW[128][68];  // pw^T[k][co]
  int n0 = blockIdx.x * 64, co0 = blockIdx.y * 64, b = blockIdx.z;
  int t = threadIdx.x;
#pragma unroll
  for (int r = 0; r < 32; ++r) {
    int e = r * 256 + t;
    int k = e >> 6, n = e & 63;
    sA[k][n] = dwt[((size_t)b * CH_FEAT + k) * NPOS + n0 + n];
  }
#pragma unroll
  for (int r = 0; r < 32; ++r) {
    int e = r * 256 + t;
    int k = e & 127, co = e >> 7;
    sW[k][co] = pw[(size_t)(co0 + co) * CH_FEAT + k];
  }
  __syncthreads();
  int tx = t & 15, ty = t >> 4;
  float acc[4][4] = {};
#pragma unroll 4
  for (int k = 0; k < 128; ++k) {
    float4 a = *(const float4*)&sA[k][tx * 4];
    float4 wv = *(const float4*)&sW[k][ty * 4];
    float av[4] = {a.x, a.y, a.z, a.w};
    float wvv[4] = {wv.x, wv.y, wv.z, wv.w};
#pragma unroll
    for (int i = 0; i < 4; ++i)
#pragma unroll
      for (int j = 0; j < 4; ++j) acc[i][j] += wvv[i] * av[j];
  }
#pragma unroll
  for (int i = 0; i < 4; ++i) {
    int co = co0 + ty * 4 + i;
    int qv = co >> 8, c2 = co & 255, head = c2 & 3, dh = c2 >> 2;
    float* dst = qv ? fv : fq;
    size_t base = (((size_t)b * HEADS + head) * NPOS) * (size_t)DH + dh;
#pragma unroll
    for (int j = 0; j < 4; ++j) {
      int n = n0 + tx * 4 + j;
      dst[base + (size_t)n * DH] = acc[i][j];
    }
  }
}

// ---------------- attention row pass: softmax over M, P @ map_v ------------
__global__ __launch_bounds__(256) void k_attn_row(const float* __restrict__ fq,
                                                  const float* __restrict__ mapq,
                                                  const float* __restrict__ mapv,
                                                  float* __restrict__ F) {
  int j = blockIdx.x * 256 + threadIdx.x;
  int bh = blockIdx.y;
  const float* qp = fq + ((size_t)bh * NPOS + j) * DH;
  float qr[64];
#pragma unroll
  for (int d = 0; d < 64; d += 4) {
    float4 v = *(const float4*)(qp + d);
    qr[d] = v.x; qr[d + 1] = v.y; qr[d + 2] = v.z; qr[d + 3] = v.w;
  }
  float acc[64];
#pragma unroll
  for (int d = 0; d < 64; ++d) acc[d] = 0.f;
  float l = 0.f;
  const float* Kp = mapq + (size_t)bh * MPOS * DH;
  const float* Vp = mapv + (size_t)bh * MPOS * DH;
  for (int i = 0; i < MPOS; ++i) {
    const float* kr = Kp + i * DH;  // uniform across lanes -> scalar loads
    float s = 0.f;
#pragma unroll
    for (int d = 0; d < 64; ++d) s += qr[d] * kr[d];
    float p = __expf(s);  // |s| << 1: no max-subtraction needed
    l += p;
    const float* vr = Vp + i * DH;
#pragma unroll
    for (int d = 0; d < 64; ++d) acc[d] += p * vr[d];
  }
  float rl = 1.f / l;
  int b = bh >> 2, head = bh & 3;
  float* Fb = F + (size_t)b * INNER * NPOS;
#pragma unroll
  for (int d = 0; d < 64; ++d)
    Fb[(size_t)(d * HEADS + head) * NPOS + j] = acc[d] * rl;  // merged-head layout
}

// ---------------- attention column pass: partial colsum + E^T @ feat_v -----
__global__ __launch_bounds__(256) void k_attn_col(const float* __restrict__ fq,
                                                  const float* __restrict__ fv,
                                                  const float* __restrict__ mapq,
                                                  float* __restrict__ G,
                                                  int jch, int jlen) {
  int i = blockIdx.x * 256 + threadIdx.x;  // column 0..511
  int bh = blockIdx.y;
  int chunk = blockIdx.z;
  int j0 = chunk * jlen;
  int j1 = j0 + jlen;
  if (j1 > NPOS) j1 = NPOS;
  const float* kp = mapq + ((size_t)bh * MPOS + i) * DH;
  float kr[64];
#pragma unroll
  for (int d = 0; d < 64; d += 4) {
    float4 v = *(const float4*)(kp + d);
    kr[d] = v.x; kr[d + 1] = v.y; kr[d + 2] = v.z; kr[d + 3] = v.w;
  }
  float acc[64];
#pragma unroll
  for (int d = 0; d < 64; ++d) acc[d] = 0.f;
  float l = 0.f;
  const float* qb = fq + (size_t)bh * NPOS * DH;
  const float* vb = fv + (size_t)bh * NPOS * DH;
  for (int j = j0; j < j1; ++j) {
    const float* qp = qb + (size_t)j * DH;  // uniform -> scalar loads
    float s = 0.f;
#pragma unroll
    for (int d = 0; d < 64; ++d) s += kr[d] * qp[d];
    float e = __expf(s);
    l += e;
    const float* vp = vb + (size_t)j * DH;
#pragma unroll
    for (int d = 0; d < 64; ++d) acc[d] += e * vp[d];
  }
  float* g = G + (((size_t)bh * jch + chunk) * MPOS + i) * 65;
#pragma unroll
  for (int d = 0; d < 64; ++d) g[d] = acc[d];
  g[64] = l;
}

// ---------------- combine column partials + map_out projection -------------
__global__ __launch_bounds__(256) void k_map_out(const float* __restrict__ G,
                                                 const float* __restrict__ mow,
                                                 float* __restrict__ out2,
                                                 int jch) {
  int m = blockIdx.x;
  int b = blockIdx.y;
  int t = threadIdx.x;
  __shared__ float sMA[256];
  __shared__ float sL[4];
  if (t < 4) {
    int bh = b * HEADS + t;
    float l = 0.f;
    for (int ch = 0; ch < jch; ++ch)
      l += G[(((size_t)bh * jch + ch) * MPOS + m) * 65 + 64];
    sL[t] = 1.f / l;
  }
  __syncthreads();
  {
    int head = t & 3, dh = t >> 2;  // channel c = dh*4+head = t
    int bh = b * HEADS + head;
    float s = 0.f;
    for (int ch = 0; ch < jch; ++ch)
      s += G[(((size_t)bh * jch + ch) * MPOS + m) * 65 + dh];
    sMA[t] = s * sL[head];
  }
  __syncthreads();
  if (t < 64) {
    const float* wr = mow + t * 256;
    float acc = 0.f;
#pragma unroll 4
    for (int c = 0; c < 256; ++c) acc += wr[c] * sMA[c];
    out2[((size_t)b * 64 + t) * MPOS + m] = acc;
  }
}

// ---------------- pointwise out GEMM: [128,256] x dwo -> out1 --------------
__global__ __launch_bounds__(256) void k_pw_out(const float* __restrict__ dwo,
                                                const float* __restrict__ pw,
                                                float* __restrict__ out1) {
  __shared__ __align__(16) float sA[128][68];
  __shared__ __align__(16) float sW[128][68];
  int n0 = blockIdx.x * 64, co0 = blockIdx.y * 64, b = blockIdx.z;
  int t = threadIdx.x;
  int tx = t & 15, ty = t >> 4;
  float acc[4][4] = {};
  for (int kk = 0; kk < 2; ++kk) {
    __syncthreads();
#pragma unroll
    for (int r = 0; r < 32; ++r) {
      int e = r * 256 + t;
      int k = e >> 6, n = e & 63;
      sA[k][n] = dwo[((size_t)b * INNER + kk * 128 + k) * NPOS + n0 + n];
    }
#pragma unroll
    for (int r = 0; r < 32; ++r) {
      int e = r * 256 + t;
      int k = e & 127, co = e >> 7;
      sW[k][co] = pw[(size_t)(co0 + co) * INNER + kk * 128 + k];
    }
    __syncthreads();
#pragma unroll 4
    for (int k = 0; k < 128; ++k) {
      float4 a = *(const float4*)&sA[k][tx * 4];
      float4 wv = *(const float4*)&sW[k][ty * 4];
      float av[4] = {a.x, a.y, a.z, a.w};
      float wvv[4] = {wv.x, wv.y, wv.z, wv.w};
#pragma unroll
      for (int i = 0; i < 4; ++i)
#pragma unroll
        for (int j = 0; j < 4; ++j) acc[i][j] += wvv[i] * av[j];
    }
  }
#pragma unroll
  for (int i = 0; i < 4; ++i) {
    int co = co0 + ty * 4 + i;
#pragma unroll
    for (int j = 0; j < 4; ++j) {
      int n = n0 + tx * 4 + j;
      out1[((size_t)b * 128 + co) * NPOS + n] = acc[i][j];
    }
  }
}

extern "C" void kernel_launch(void* const* d_in, const int* in_sizes, int n_in,
                              void* d_out, int out_size, void* d_ws, size_t ws_size,
                              hipStream_t stream) {
  const float* feat = (const float*)d_in[0];
  const float* smap = (const float*)d_in[1];
  const float* fqv_dw = (const float*)d_in[2];
  const float* fqv_pw = (const float*)d_in[3];
  const float* fout_dw = (const float*)d_in[4];
  const float* fout_pw = (const float*)d_in[5];
  const float* mqv_w = (const float*)d_in[6];
  const float* mout_w = (const float*)d_in[7];

  float* out = (float*)d_out;
  float* out1 = out;                              // [2,128,24,24,24]
  float* out2 = out + (size_t)BB * 128 * NPOS;    // [2,64,8,8,8]

  float* ws = (float*)d_ws;
  const size_t QV = (size_t)BB * HEADS * NPOS * DH;    // 7,077,888
  const size_t MQV = (size_t)BB * HEADS * MPOS * DH;   // 262,144
  float* fq = ws;
  float* fv = fq + QV;
  float* F = fv + QV;
  float* mapq = F + QV;
  float* mapv = mapq + MQV;
  float* G = mapv + MQV;
  size_t base_floats = (size_t)(G - ws);

  // dwt lives in d_out (fits in the out1 region); dwo reuses fq after col pass
  float* dwt = out1;
  float* dwo = fq;

  long avail = (long)(ws_size / 4) - (long)base_floats;
  int jch = (int)(avail / (4096L * 65L));
  if (jch < 1) jch = 1;
  if (jch > 32) jch = 32;
  int jlen = (NPOS + jch - 1) / jch;

  k_map_qv<<<dim3(BB * MPOS), dim3(512), 0, stream>>>(smap, mqv_w, mapq, mapv);
  k_dw<<<dim3(BB * CH_FEAT * NPOS / 256), dim3(256), 0, stream>>>(feat, fqv_dw, dwt, CH_FEAT);
  k_pw_qv<<<dim3(NPOS / 64, 8, BB), dim3(256), 0, stream>>>(dwt, fqv_pw, fq, fv);
  k_attn_row<<<dim3(NPOS / 256, BB * HEADS), dim3(256), 0, stream>>>(fq, mapq, mapv, F);
  k_attn_col<<<dim3(2, BB * HEADS, jch), dim3(256), 0, stream>>>(fq, fv, mapq, G, jch, jlen);
  k_map_out<<<dim3(MPOS, BB), dim3(256), 0, stream>>>(G, mout_w, out2, jch);
  k_dw<<<dim3(BB * INNER * NPOS / 256), dim3(256), 0, stream>>>(F, fout_dw, dwo, INNER);
  k_pw_out<<<dim3(NPOS / 64, 2, BB), dim3(256), 0, stream>>>(dwo, fout_pw, out1);
}